// Round 7
// baseline (42.046 us; speedup 1.0000x reference)
//
#include <hip/hip_runtime.h>
#include <stdint.h>

#define HH 2048
#define WW 2048
#define NPIX (HH*WW)
#define TS 64
#define NBX (WW/TS)      // 32
#define NBY (HH/TS)      // 32
#define NBLK (NBX*NBY)   // 1024 fused blocks
#define HR (TS+8)        // 72 halo'd rows
#define QW 18            // quads per halo'd row (72 cols)
#define BST 24           // bmask row stride (18 nibble-bytes + 6 pad)
#define MW 3             // packed mask words per halo'd row (72 bits)

// ---------------- Fused kernel: fw+mask (LDS-only) + contour -> byte code ----------------
// 64x64 tile + own +-4 halo re-read from target (1.266x read amp buys out the
// A->B global barrier, fw/mask round-trip, and a launch gap; B's VALU hides
// under the HBM read via inter-block overlap).
// Code byte = ((enc-1)<<3)|fw, enc = mind2 (<=32) or 26 ("none"; 26 = a^2+b^2
// unachievable for a,b<=4).
__global__ __launch_bounds__(256, 2) void fused_kernel(
    const float* __restrict__ target, const float* __restrict__ dk,
    uint8_t* __restrict__ wcode, float* __restrict__ pmin, float* __restrict__ pmax)
{
    __shared__ uint8_t  bmask[HR * BST];   // nibble-per-quad combined bits
    __shared__ uint32_t maskw[HR][MW];     // bit-packed halo'd rows
    __shared__ uint8_t  lutm2[512];        // 9-bit diff-mask -> min|dx|^2 (8->64)
    __shared__ float    inv_ext[65];       // d^2 -> 1/dist, 0 if unachievable/none(64)
    __shared__ float    redmn[4], redmx[4];

    const int t   = threadIdx.x;
    const int gx0 = blockIdx.x * TS;
    const int gy0 = blockIdx.y * TS;
    const float4* t4 = (const float4*)target;

    // ---- phase L: tables, zero-pads, interior+ring loads -> nibbles ----
    for (int idx = t; idx < 512; idx += 256) {
        uint32_t rev = __builtin_bitreverse32((uint32_t)idx) >> 23;   // dx -> -dx
        uint32_t g = ((((uint32_t)idx | rev) >> 4) & 0x1Fu) | 0x100u;
        uint32_t mk = (uint32_t)__builtin_ctz(g);                     // min|dx| or 8
        lutm2[idx] = (uint8_t)(mk * mk);
    }
    if (t < 65) inv_ext[t] = 0.0f;          // filled (after barrier) in phase P
    if (t < HR) {                           // zero pad bytes 18..23 of each row
        uint16_t* p = (uint16_t*)(bmask + t * BST + 18);
        p[0] = 0; p[1] = 0; p[2] = 0;
    }

    // interior: 512 groups of 8px; thread owns groups t, t+256 (fw stays in regs)
    uint32_t fwl[2], fwh[2];
    #pragma unroll
    for (int gi = 0; gi < 2; ++gi) {
        int g = t + gi * 256;
        int r = g >> 3, xg = g & 7;
        int qb = (gy0 + r) * (WW / 4) + (gx0 >> 2) + xg * 2;
        float4 a0 = t4[qb],                 a1 = t4[qb + 1];
        float4 b0 = t4[qb +     NPIX / 4],  b1 = t4[qb + 1 +     NPIX / 4];
        float4 c0 = t4[qb + 2 * (NPIX/4)],  c1 = t4[qb + 1 + 2 * (NPIX/4)];
        float4 d0 = t4[qb + 3 * (NPIX/4)],  d1 = t4[qb + 1 + 3 * (NPIX/4)];
        float4 e0 = t4[qb + 4 * (NPIX/4)],  e1 = t4[qb + 1 + 4 * (NPIX/4)];
        float f0 = a0.x+b0.x+c0.x+d0.x+e0.x, f1 = a0.y+b0.y+c0.y+d0.y+e0.y;
        float f2 = a0.z+b0.z+c0.z+d0.z+e0.z, f3 = a0.w+b0.w+c0.w+d0.w+e0.w;
        float f4 = a1.x+b1.x+c1.x+d1.x+e1.x, f5 = a1.y+b1.y+c1.y+d1.y+e1.y;
        float f6 = a1.z+b1.z+c1.z+d1.z+e1.z, f7 = a1.w+b1.w+c1.w+d1.w+e1.w;
        fwl[gi] = (uint32_t)f0 | ((uint32_t)f1 << 8) | ((uint32_t)f2 << 16) | ((uint32_t)f3 << 24);
        fwh[gi] = (uint32_t)f4 | ((uint32_t)f5 << 8) | ((uint32_t)f6 << 16) | ((uint32_t)f7 << 24);
        uint32_t nib0 = (f0!=0.f?1u:0u)|(f1!=0.f?2u:0u)|(f2!=0.f?4u:0u)|(f3!=0.f?8u:0u);
        uint32_t nib1 = (f4!=0.f?1u:0u)|(f5!=0.f?2u:0u)|(f6!=0.f?4u:0u)|(f7!=0.f?8u:0u);
        bmask[(4 + r) * BST + 1 + 2 * xg] = (uint8_t)nib0;   // interior quads 1..16
        bmask[(4 + r) * BST + 2 + 2 * xg] = (uint8_t)nib1;
    }

    // ring: 8 full halo rows x 18 quads + 64 rows x {q0, q17} = 272 quad tasks
    for (int idx = t; idx < 272; idx += 256) {
        int hy, q;
        if (idx < 144) { int h = idx / QW; q = idx - h * QW; hy = (h < 4) ? h : h + 64; }
        else           { int j = idx - 144; hy = 4 + (j >> 1); q = (j & 1) ? (QW - 1) : 0; }
        int gy = gy0 - 4 + hy; gy = min(max(gy, 0), HH - 1);       // row edge-clamp
        int col0 = gx0 - 4 + 4 * q;
        int qx = col0 >> 2; qx = min(max(qx, 0), WW / 4 - 1);      // col quad clamp
        int qb = gy * (WW / 4) + qx;
        float4 a = t4[qb],               b = t4[qb +     NPIX / 4];
        float4 c = t4[qb + 2*(NPIX/4)],  d = t4[qb + 3 * (NPIX/4)];
        float4 e = t4[qb + 4*(NPIX/4)];
        float f0 = a.x+b.x+c.x+d.x+e.x, f1 = a.y+b.y+c.y+d.y+e.y;
        float f2 = a.z+b.z+c.z+d.z+e.z, f3 = a.w+b.w+c.w+d.w+e.w;
        uint32_t nib = (f0!=0.f?1u:0u)|(f1!=0.f?2u:0u)|(f2!=0.f?4u:0u)|(f3!=0.f?8u:0u);
        if (col0 < 0)    nib = (nib & 1u) * 0xFu;     // left image edge: replicate col 0
        if (col0 >= WW)  nib = (nib >> 3) * 0xFu;     // right image edge: replicate col 2047
        bmask[hy * BST + q] = (uint8_t)nib;
    }
    __syncthreads();

    // ---- phase P: inverse-distance fill + nibble->bit pack ----
    if (t < 81) {
        int iy = t / 9, jx = t - (t / 9) * 9;
        int dy = iy - 4, dx = jx - 4;
        int d2 = dy * dy + dx * dx;
        if (d2 != 0) inv_ext[d2] = 1.0f / (dk[t] / (1.0f + 1e-10f) + 1e-10f);
    }
    if (t < HR * MW) {                      // 216 pack tasks
        int hy = t / MW, ws = t - (t / MW) * MW;
        uint32_t v0 = *(const uint32_t*)(bmask + hy * BST + 8 * ws);
        uint32_t v1 = *(const uint32_t*)(bmask + hy * BST + 8 * ws + 4);
        v0 = (v0 | (v0 >> 4)) & 0x00FF00FFu; v0 = (v0 | (v0 >> 8)) & 0xFFFFu;
        v1 = (v1 | (v1 >> 4)) & 0x00FF00FFu; v1 = (v1 | (v1 >> 8)) & 0xFFFFu;
        maskw[hy][ws] = v0 | (v1 << 16);
    }
    __syncthreads();

    // ---- phase C: contour + code + min/max ----
    float lmn = __int_as_float(0x7F800000);
    float lmx = 0.0f;
    #pragma unroll
    for (int gi = 0; gi < 2; ++gi) {
        int g = t + gi * 256;
        int r = g >> 3, xg = g & 7;
        const int wsel = xg >> 2;
        const uint32_t sh = (uint32_t)((8 * xg) & 31);
        uint32_t wrow[9];                   // bit i = col gx0-4+8xg+i
        #pragma unroll
        for (int k = 0; k < 9; ++k) {
            uint64_t v = (((uint64_t)maskw[r + k][wsel + 1]) << 32) | maskw[r + k][wsel];
            wrow[k] = (uint32_t)(v >> sh);
        }
        // row-pair fold: diff(+k)|diff(-k) = (center ? ~(r+ & r-) : (r+ | r-)) = sel^cm
        uint32_t orx[4], andx[4];
        #pragma unroll
        for (int k = 1; k <= 4; ++k) {
            orx[k-1]  = wrow[4 - k] | wrow[4 + k];
            andx[k-1] = wrow[4 - k] & wrow[4 + k];
        }
        uint32_t outb0 = 0, outb1 = 0;
        #pragma unroll
        for (int j = 0; j < 8; ++j) {
            uint32_t craw = (wrow[4] >> (4 + j)) & 1u;
            uint32_t cm = 0u - craw;
            uint32_t x0 = ((wrow[4] ^ cm) >> j) & 0x1FFu;     // dy=0 (center self-0)
            uint32_t d2m = (uint32_t)lutm2[x0];               // in {1,4,9,16,64}
            #pragma unroll
            for (int k = 1; k <= 4; ++k) {
                uint32_t sel = craw ? andx[k-1] : orx[k-1];
                uint32_t x = ((sel ^ cm) >> j) & 0x1FFu;
                uint32_t d2 = (uint32_t)lutm2[x] + (uint32_t)(k * k);
                d2m = min(d2m, d2);
            }
            float contour = inv_ext[d2m];                     // 0 for "none"(64)
            uint32_t enc = (d2m > 32u) ? 26u : d2m;
            uint32_t fwj = (j < 4 ? (fwl[gi] >> (8 * j)) : (fwh[gi] >> (8 * (j - 4)))) & 0xFFu;
            uint32_t code = ((enc - 1u) << 3) | fwj;
            if (j < 4) outb0 |= code << (8 * j);
            else       outb1 |= code << (8 * (j - 4));
            float wv = (float)fwj + contour;
            wv = wv * wv;
            lmn = fminf(lmn, wv);
            lmx = fmaxf(lmx, wv);
        }
        uint2 ob; ob.x = outb0; ob.y = outb1;
        *(uint2*)(wcode + (gy0 + r) * WW + gx0 + 8 * xg) = ob;
    }

    // block reduce -> one plain store pair (same-address atomics = round-2 disaster)
    #pragma unroll
    for (int off = 32; off > 0; off >>= 1) {
        lmn = fminf(lmn, __shfl_xor(lmn, off));
        lmx = fmaxf(lmx, __shfl_xor(lmx, off));
    }
    if ((t & 63) == 0) { redmn[t >> 6] = lmn; redmx[t >> 6] = lmx; }
    __syncthreads();
    if (t == 0) {
        float mn = fminf(fminf(redmn[0], redmn[1]), fminf(redmn[2], redmn[3]));
        float mx = fmaxf(fmaxf(redmx[0], redmx[1]), fmaxf(redmx[2], redmx[3]));
        int bid = blockIdx.y * NBX + blockIdx.x;
        pmin[bid] = mn;
        pmax[bid] = mx;
    }
}

// ---------------- Kernel C: redundant partial-reduce + LUT decode + normalize ----------------
// 2048 blocks x 256 threads, 8 px/thread; w rebuilt bit-exactly from code byte.
__global__ __launch_bounds__(256) void norm_kernel(
    const uint8_t* __restrict__ wcode, const float* __restrict__ dk,
    const float* __restrict__ pmin, const float* __restrict__ pmax,
    float* __restrict__ out)
{
    __shared__ float ct[33];       // d^2 -> 1/dist (0 where none, incl code 26)
    __shared__ float wlut[256];    // code byte -> w value
    __shared__ float smn[4], smx[4];
    const int t = threadIdx.x;

    if (t < 33) ct[t] = 0.0f;
    // load the 1024 partial pairs while table phases run
    const float4* pn4 = (const float4*)pmin;
    const float4* px4 = (const float4*)pmax;
    float4 a = pn4[t];
    float4 c = px4[t];
    __syncthreads();
    if (t < 81) {
        int iy = t / 9, jx = t - (t / 9) * 9;
        int dy = iy - 4, dx = jx - 4;
        int d2 = dy * dy + dx * dx;
        if (d2 != 0) ct[d2] = 1.0f / (dk[t] / (1.0f + 1e-10f) + 1e-10f);
    }
    __syncthreads();
    {   // decode LUT: identical arithmetic to fused kernel -> bit-exact
        float wv = (float)(t & 7) + ct[(t >> 3) + 1];
        wlut[t] = wv * wv;
    }
    float mn = fminf(fminf(a.x, a.y), fminf(a.z, a.w));
    float mx = fmaxf(fmaxf(c.x, c.y), fmaxf(c.z, c.w));
    #pragma unroll
    for (int off = 32; off > 0; off >>= 1) {
        mn = fminf(mn, __shfl_xor(mn, off));
        mx = fmaxf(mx, __shfl_xor(mx, off));
    }
    if ((t & 63) == 0) { smn[t >> 6] = mn; smx[t >> 6] = mx; }
    __syncthreads();
    mn = fminf(fminf(smn[0], smn[1]), fminf(smn[2], smn[3]));
    mx = fmaxf(fmaxf(smx[0], smx[1]), fmaxf(smx[2], smx[3]));
    const float rden = 1.0f / (mx - mn + 1e-10f);

    const int i = blockIdx.x * 256 + t;          // 8-px group id
    uint2 cb = ((const uint2*)wcode)[i];
    uint32_t b0 = cb.x, b1 = cb.y;
    float4 o0, o1;
    o0.x = (b0 & 7u)         ? (wlut[b0 & 0xFFu] - mn) * rden         : 0.0f;
    o0.y = ((b0 >> 8) & 7u)  ? (wlut[(b0 >> 8) & 0xFFu] - mn) * rden  : 0.0f;
    o0.z = ((b0 >> 16) & 7u) ? (wlut[(b0 >> 16) & 0xFFu] - mn) * rden : 0.0f;
    o0.w = ((b0 >> 24) & 7u) ? (wlut[b0 >> 24] - mn) * rden           : 0.0f;
    o1.x = (b1 & 7u)         ? (wlut[b1 & 0xFFu] - mn) * rden         : 0.0f;
    o1.y = ((b1 >> 8) & 7u)  ? (wlut[(b1 >> 8) & 0xFFu] - mn) * rden  : 0.0f;
    o1.z = ((b1 >> 16) & 7u) ? (wlut[(b1 >> 16) & 0xFFu] - mn) * rden : 0.0f;
    o1.w = ((b1 >> 24) & 7u) ? (wlut[b1 >> 24] - mn) * rden           : 0.0f;
    ((float4*)out)[i * 2]     = o0;
    ((float4*)out)[i * 2 + 1] = o1;
}

extern "C" void kernel_launch(void* const* d_in, const int* in_sizes, int n_in,
                              void* d_out, int out_size, void* d_ws, size_t ws_size,
                              hipStream_t stream)
{
    const float* target = (const float*)d_in[0];
    const float* dk     = (const float*)d_in[1];
    float* out = (float*)d_out;

    uint8_t* wsb = (uint8_t*)d_ws;
    uint8_t* wcode = wsb;                        // 4 MB u8 code plane
    float*   pmin  = (float*)(wsb + NPIX);       // 4 KB partial mins
    float*   pmax  = pmin + NBLK;                // 4 KB partial maxs

    fused_kernel<<<dim3(NBX, NBY), 256, 0, stream>>>(target, dk, wcode, pmin, pmax);

    norm_kernel<<<NPIX / 8 / 256, 256, 0, stream>>>(wcode, dk, pmin, pmax, out);
}

// Round 8
// 39.614 us; speedup vs baseline: 1.0614x; 1.0614x over previous
//
#include <hip/hip_runtime.h>
#include <stdint.h>

#define HH 2048
#define WW 2048
#define NPIX (HH*WW)
#define TS 64
#define NBX (WW/TS)      // 32
#define NBY (HH/TS)      // 32
#define NBLK (NBX*NBY)   // 1024 fused blocks
#define HR (TS+8)        // 72 halo'd rows
#define QW 18            // quads per halo'd row (72 cols)
#define BST 24           // bmask row stride (18 nibble-bytes + 6 pad)
#define MW 3             // packed mask words per halo'd row (72 bits)

// ---------------- Fused kernel: fw+mask (LDS-only) + contour -> byte code ----------------
// 64x64 tile + own +-4 halo re-read from target. Round-7 lesson: 2 groups/thread
// held 20 float4 loads live -> >256 VGPR -> 1 block/CU -> 2.9 TB/s. Now 512
// threads x 1 group (10 in-flight float4, ~60 live regs) to restore occupancy
// and memory-level parallelism.
// Code byte = ((enc-1)<<3)|fw, enc = mind2 (<=32) or 26 ("none"; 26 = a^2+b^2
// unachievable for a,b<=4).
__global__ __launch_bounds__(512, 2) void fused_kernel(
    const float* __restrict__ target, const float* __restrict__ dk,
    uint8_t* __restrict__ wcode, float* __restrict__ pmin, float* __restrict__ pmax)
{
    __shared__ uint8_t  bmask[HR * BST];   // nibble-per-quad combined bits
    __shared__ uint32_t maskw[HR][MW];     // bit-packed halo'd rows
    __shared__ uint8_t  lutm2[512];        // 9-bit diff-mask -> min|dx|^2 (8->64)
    __shared__ float    inv_ext[65];       // d^2 -> 1/dist, 0 if unachievable/none(64)
    __shared__ float    redmn[8], redmx[8];

    const int t   = threadIdx.x;
    const int gx0 = blockIdx.x * TS;
    const int gy0 = blockIdx.y * TS;
    const float4* t4 = (const float4*)target;

    // ---- phase L: tables, zero-pads, interior+ring loads -> nibbles ----
    {   // one LUT entry per thread (512 threads)
        uint32_t rev = __builtin_bitreverse32((uint32_t)t) >> 23;     // dx -> -dx
        uint32_t g = ((((uint32_t)t | rev) >> 4) & 0x1Fu) | 0x100u;
        uint32_t mk = (uint32_t)__builtin_ctz(g);                     // min|dx| or 8
        lutm2[t] = (uint8_t)(mk * mk);
    }
    if (t < 65) inv_ext[t] = 0.0f;          // filled (after barrier) in phase P
    if (t < HR) {                           // zero pad bytes 18..23 of each row
        uint16_t* p = (uint16_t*)(bmask + t * BST + 18);
        p[0] = 0; p[1] = 0; p[2] = 0;
    }

    // interior: one 8-px group per thread (fw stays in regs)
    const int r  = t >> 3;                  // tile row 0..63
    const int xg = t & 7;                   // 8-px group in row
    uint32_t fwl, fwh;
    {
        int qb = (gy0 + r) * (WW / 4) + (gx0 >> 2) + xg * 2;
        float4 a0 = t4[qb],                 a1 = t4[qb + 1];
        float4 b0 = t4[qb +     NPIX / 4],  b1 = t4[qb + 1 +     NPIX / 4];
        float4 c0 = t4[qb + 2 * (NPIX/4)],  c1 = t4[qb + 1 + 2 * (NPIX/4)];
        float4 d0 = t4[qb + 3 * (NPIX/4)],  d1 = t4[qb + 1 + 3 * (NPIX/4)];
        float4 e0 = t4[qb + 4 * (NPIX/4)],  e1 = t4[qb + 1 + 4 * (NPIX/4)];
        float f0 = a0.x+b0.x+c0.x+d0.x+e0.x, f1 = a0.y+b0.y+c0.y+d0.y+e0.y;
        float f2 = a0.z+b0.z+c0.z+d0.z+e0.z, f3 = a0.w+b0.w+c0.w+d0.w+e0.w;
        float f4 = a1.x+b1.x+c1.x+d1.x+e1.x, f5 = a1.y+b1.y+c1.y+d1.y+e1.y;
        float f6 = a1.z+b1.z+c1.z+d1.z+e1.z, f7 = a1.w+b1.w+c1.w+d1.w+e1.w;
        fwl = (uint32_t)f0 | ((uint32_t)f1 << 8) | ((uint32_t)f2 << 16) | ((uint32_t)f3 << 24);
        fwh = (uint32_t)f4 | ((uint32_t)f5 << 8) | ((uint32_t)f6 << 16) | ((uint32_t)f7 << 24);
        uint32_t nib0 = (f0!=0.f?1u:0u)|(f1!=0.f?2u:0u)|(f2!=0.f?4u:0u)|(f3!=0.f?8u:0u);
        uint32_t nib1 = (f4!=0.f?1u:0u)|(f5!=0.f?2u:0u)|(f6!=0.f?4u:0u)|(f7!=0.f?8u:0u);
        bmask[(4 + r) * BST + 1 + 2 * xg] = (uint8_t)nib0;   // interior quads 1..16
        bmask[(4 + r) * BST + 2 + 2 * xg] = (uint8_t)nib1;
    }

    // ring: 8 full halo rows x 18 quads + 64 rows x {q0, q17} = 272 quad tasks
    if (t < 272) {
        int hy, q;
        if (t < 144) { int h = t / QW; q = t - h * QW; hy = (h < 4) ? h : h + 64; }
        else         { int j = t - 144; hy = 4 + (j >> 1); q = (j & 1) ? (QW - 1) : 0; }
        int gy = gy0 - 4 + hy; gy = min(max(gy, 0), HH - 1);       // row edge-clamp
        int col0 = gx0 - 4 + 4 * q;
        int qx = col0 >> 2; qx = min(max(qx, 0), WW / 4 - 1);      // col quad clamp
        int qb = gy * (WW / 4) + qx;
        float4 a = t4[qb],               b = t4[qb +     NPIX / 4];
        float4 c = t4[qb + 2*(NPIX/4)],  d = t4[qb + 3 * (NPIX/4)];
        float4 e = t4[qb + 4*(NPIX/4)];
        float f0 = a.x+b.x+c.x+d.x+e.x, f1 = a.y+b.y+c.y+d.y+e.y;
        float f2 = a.z+b.z+c.z+d.z+e.z, f3 = a.w+b.w+c.w+d.w+e.w;
        uint32_t nib = (f0!=0.f?1u:0u)|(f1!=0.f?2u:0u)|(f2!=0.f?4u:0u)|(f3!=0.f?8u:0u);
        if (col0 < 0)    nib = (nib & 1u) * 0xFu;     // left image edge: replicate col 0
        if (col0 >= WW)  nib = (nib >> 3) * 0xFu;     // right image edge: replicate col 2047
        bmask[hy * BST + q] = (uint8_t)nib;
    }
    __syncthreads();

    // ---- phase P: inverse-distance fill + nibble->bit pack ----
    if (t < 81) {
        int iy = t / 9, jx = t - (t / 9) * 9;
        int dy = iy - 4, dx = jx - 4;
        int d2 = dy * dy + dx * dx;
        if (d2 != 0) inv_ext[d2] = 1.0f / (dk[t] / (1.0f + 1e-10f) + 1e-10f);
    }
    if (t < HR * MW) {                      // 216 pack tasks
        int hy = t / MW, ws = t - (t / MW) * MW;
        uint32_t v0 = *(const uint32_t*)(bmask + hy * BST + 8 * ws);
        uint32_t v1 = *(const uint32_t*)(bmask + hy * BST + 8 * ws + 4);
        v0 = (v0 | (v0 >> 4)) & 0x00FF00FFu; v0 = (v0 | (v0 >> 8)) & 0xFFFFu;
        v1 = (v1 | (v1 >> 4)) & 0x00FF00FFu; v1 = (v1 | (v1 >> 8)) & 0xFFFFu;
        maskw[hy][ws] = v0 | (v1 << 16);
    }
    __syncthreads();

    // ---- phase C: contour + code + min/max (one 8-px group per thread) ----
    float lmn = __int_as_float(0x7F800000);
    float lmx = 0.0f;
    {
        const int wsel = xg >> 2;
        const uint32_t sh = (uint32_t)((8 * xg) & 31);
        uint32_t wrow[9];                   // bit i = col gx0-4+8xg+i
        #pragma unroll
        for (int k = 0; k < 9; ++k) {
            uint64_t v = (((uint64_t)maskw[r + k][wsel + 1]) << 32) | maskw[r + k][wsel];
            wrow[k] = (uint32_t)(v >> sh);
        }
        // row-pair fold: diff(+k)|diff(-k) = (center ? ~(r+ & r-) : (r+ | r-)) = sel^cm
        uint32_t orx[4], andx[4];
        #pragma unroll
        for (int k = 1; k <= 4; ++k) {
            orx[k-1]  = wrow[4 - k] | wrow[4 + k];
            andx[k-1] = wrow[4 - k] & wrow[4 + k];
        }
        uint32_t outb0 = 0, outb1 = 0;
        #pragma unroll
        for (int j = 0; j < 8; ++j) {
            uint32_t craw = (wrow[4] >> (4 + j)) & 1u;
            uint32_t cm = 0u - craw;
            uint32_t x0 = ((wrow[4] ^ cm) >> j) & 0x1FFu;     // dy=0 (center self-0)
            uint32_t d2m = (uint32_t)lutm2[x0];               // in {1,4,9,16,64}
            #pragma unroll
            for (int k = 1; k <= 4; ++k) {
                uint32_t sel = craw ? andx[k-1] : orx[k-1];
                uint32_t x = ((sel ^ cm) >> j) & 0x1FFu;
                uint32_t d2 = (uint32_t)lutm2[x] + (uint32_t)(k * k);
                d2m = min(d2m, d2);
            }
            float contour = inv_ext[d2m];                     // 0 for "none"(64)
            uint32_t enc = (d2m > 32u) ? 26u : d2m;
            uint32_t fwj = (j < 4 ? (fwl >> (8 * j)) : (fwh >> (8 * (j - 4)))) & 0xFFu;
            uint32_t code = ((enc - 1u) << 3) | fwj;
            if (j < 4) outb0 |= code << (8 * j);
            else       outb1 |= code << (8 * (j - 4));
            float wv = (float)fwj + contour;
            wv = wv * wv;
            lmn = fminf(lmn, wv);
            lmx = fmaxf(lmx, wv);
        }
        uint2 ob; ob.x = outb0; ob.y = outb1;
        *(uint2*)(wcode + (gy0 + r) * WW + gx0 + 8 * xg) = ob;
    }

    // block reduce -> one plain store pair (same-address atomics = round-2 disaster)
    #pragma unroll
    for (int off = 32; off > 0; off >>= 1) {
        lmn = fminf(lmn, __shfl_xor(lmn, off));
        lmx = fmaxf(lmx, __shfl_xor(lmx, off));
    }
    if ((t & 63) == 0) { redmn[t >> 6] = lmn; redmx[t >> 6] = lmx; }
    __syncthreads();
    if (t == 0) {
        float mn = redmn[0], mx = redmx[0];
        #pragma unroll
        for (int i = 1; i < 8; ++i) { mn = fminf(mn, redmn[i]); mx = fmaxf(mx, redmx[i]); }
        int bid = blockIdx.y * NBX + blockIdx.x;
        pmin[bid] = mn;
        pmax[bid] = mx;
    }
}

// ---------------- Kernel C: redundant partial-reduce + LUT decode + normalize ----------------
// 2048 blocks x 256 threads, 8 px/thread; w rebuilt bit-exactly from code byte.
__global__ __launch_bounds__(256) void norm_kernel(
    const uint8_t* __restrict__ wcode, const float* __restrict__ dk,
    const float* __restrict__ pmin, const float* __restrict__ pmax,
    float* __restrict__ out)
{
    __shared__ float ct[33];       // d^2 -> 1/dist (0 where none, incl code 26)
    __shared__ float wlut[256];    // code byte -> w value
    __shared__ float smn[4], smx[4];
    const int t = threadIdx.x;

    if (t < 33) ct[t] = 0.0f;
    // load the 1024 partial pairs while table phases run
    const float4* pn4 = (const float4*)pmin;
    const float4* px4 = (const float4*)pmax;
    float4 a = pn4[t];
    float4 c = px4[t];
    __syncthreads();
    if (t < 81) {
        int iy = t / 9, jx = t - (t / 9) * 9;
        int dy = iy - 4, dx = jx - 4;
        int d2 = dy * dy + dx * dx;
        if (d2 != 0) ct[d2] = 1.0f / (dk[t] / (1.0f + 1e-10f) + 1e-10f);
    }
    __syncthreads();
    {   // decode LUT: identical arithmetic to fused kernel -> bit-exact
        float wv = (float)(t & 7) + ct[(t >> 3) + 1];
        wlut[t] = wv * wv;
    }
    float mn = fminf(fminf(a.x, a.y), fminf(a.z, a.w));
    float mx = fmaxf(fmaxf(c.x, c.y), fmaxf(c.z, c.w));
    #pragma unroll
    for (int off = 32; off > 0; off >>= 1) {
        mn = fminf(mn, __shfl_xor(mn, off));
        mx = fmaxf(mx, __shfl_xor(mx, off));
    }
    if ((t & 63) == 0) { smn[t >> 6] = mn; smx[t >> 6] = mx; }
    __syncthreads();
    mn = fminf(fminf(smn[0], smn[1]), fminf(smn[2], smn[3]));
    mx = fmaxf(fmaxf(smx[0], smx[1]), fmaxf(smx[2], smx[3]));
    const float rden = 1.0f / (mx - mn + 1e-10f);

    const int i = blockIdx.x * 256 + t;          // 8-px group id
    uint2 cb = ((const uint2*)wcode)[i];
    uint32_t b0 = cb.x, b1 = cb.y;
    float4 o0, o1;
    o0.x = (b0 & 7u)         ? (wlut[b0 & 0xFFu] - mn) * rden         : 0.0f;
    o0.y = ((b0 >> 8) & 7u)  ? (wlut[(b0 >> 8) & 0xFFu] - mn) * rden  : 0.0f;
    o0.z = ((b0 >> 16) & 7u) ? (wlut[(b0 >> 16) & 0xFFu] - mn) * rden : 0.0f;
    o0.w = ((b0 >> 24) & 7u) ? (wlut[b0 >> 24] - mn) * rden           : 0.0f;
    o1.x = (b1 & 7u)         ? (wlut[b1 & 0xFFu] - mn) * rden         : 0.0f;
    o1.y = ((b1 >> 8) & 7u)  ? (wlut[(b1 >> 8) & 0xFFu] - mn) * rden  : 0.0f;
    o1.z = ((b1 >> 16) & 7u) ? (wlut[(b1 >> 16) & 0xFFu] - mn) * rden : 0.0f;
    o1.w = ((b1 >> 24) & 7u) ? (wlut[b1 >> 24] - mn) * rden           : 0.0f;
    ((float4*)out)[i * 2]     = o0;
    ((float4*)out)[i * 2 + 1] = o1;
}

extern "C" void kernel_launch(void* const* d_in, const int* in_sizes, int n_in,
                              void* d_out, int out_size, void* d_ws, size_t ws_size,
                              hipStream_t stream)
{
    const float* target = (const float*)d_in[0];
    const float* dk     = (const float*)d_in[1];
    float* out = (float*)d_out;

    uint8_t* wsb = (uint8_t*)d_ws;
    uint8_t* wcode = wsb;                        // 4 MB u8 code plane
    float*   pmin  = (float*)(wsb + NPIX);       // 4 KB partial mins
    float*   pmax  = pmin + NBLK;                // 4 KB partial maxs

    fused_kernel<<<dim3(NBX, NBY), 512, 0, stream>>>(target, dk, wcode, pmin, pmax);

    norm_kernel<<<NPIX / 8 / 256, 256, 0, stream>>>(wcode, dk, pmin, pmax, out);
}